// Round 8
// baseline (511.668 us; speedup 1.0000x reference)
//
#include <hip/hip_runtime.h>
#include <hip/hip_bf16.h>

// x[16,32,32,32,32] f32, w[32,64,3,3,3] f32, b[64] f32
// ConvTranspose3d(s=2,p=1,k=3) -> (+bias)*0.5 -> maxpool2 -> mean -> clamp[0,1] -> out[16,64]
//
// Window algebra (validated R0/R1, HW re-verified R10/R12): window w covers conv
// outputs {2w,2w+1}/dim, inputs {w,w+1}/dim. MFMA 16x16x32 bf16: M=16 ww-windows,
// N=16 co, K=32=Cin. Tap->frag rule: (kd,kh,kw) uses frag[dd=(kd==0)][dw=(kw==0)]
// of row wh+(kh==0).
//
// R14: phase-stagger probe on R0's proven shell (NO register changes).
// Ledger: R1/R7 (intra-phase work) flat; R8/R9/R11/R13 (reg restructures) spill —
// Bf[27] must stay allocator-placed (AGPR). Model: per SIMD, 2 co-resident waves
// from blocks (n, n+256) are wall-clock phase-locked (co-dispatch, identical
// cadence): MFMA bursts coincide (pipe saturated), combine/F-read VALU phases
// coincide (pipe IDLE ~20%+). MfmaUtil 44 + VALU 36 + waits 20 = the m114
// signature without the interleave. Fix: (a) odd (bid>>8)&1 blocks s_sleep ~1150
// cyc (= half window-slot) after the stage barrier -> persistent pi phase shift;
// (b) s_setprio(1) around the burst so the burst-phase wave owns issue;
// (c) R12's verified end-mask (-12 VALU/window).
//
// ws: [0,4096)B accS[16][64] f32; [4096,...) wB bf16 [cotile4][T27][lane64][j8],
// T in exact consumption order (see TAP tables).

typedef __bf16 bf16x8 __attribute__((ext_vector_type(8)));
typedef float  f32x4  __attribute__((ext_vector_type(4)));
typedef unsigned short ushort_t;
typedef ushort_t ushort8 __attribute__((ext_vector_type(8)));

#define NWIN 29791  // 31^3

__device__ inline ushort_t f2bf(float f) {
    unsigned u = __builtin_bit_cast(unsigned, f);
    u += 0x7FFFu + ((u >> 16) & 1u);   // RNE
    return (ushort_t)(u >> 16);
}

// Consumption-order tap list (kd,kh,kw) for T=0..26
__device__ __constant__ const unsigned char TKD[27] = {2,0,2,0,2,0,2,0, 1,0,1,2,1,0,1,2, 0,1,2,1,0,1,2,1, 0,1,2};
__device__ __constant__ const unsigned char TKH[27] = {0,0,0,0,2,2,2,2, 0,1,0,1,2,1,2,1, 0,1,0,0,2,1,2,2, 1,1,1};
__device__ __constant__ const unsigned char TKW[27] = {0,0,2,2,0,0,2,2, 0,0,2,0,0,2,2,2, 1,0,1,1,1,2,1,1, 1,1,1};

__global__ __launch_bounds__(256) void prep_kernel(const float* __restrict__ w,
                                                   float* __restrict__ ws) {
    int idx = blockIdx.x * 256 + threadIdx.x;
    if (idx < 1024) ws[idx] = 0.f;
    if (idx < 55296) {
        ushort_t* wB = (ushort_t*)((char*)ws + 4096);
        int j = idx & 7;
        int l = (idx >> 3) & 63;
        int q = idx >> 9;           // [0,108) = c*27+T
        int T = q % 27;
        int c = q / 27;
        int ci = ((l >> 4) << 3) + j;
        int co = (c << 4) + (l & 15);
        int k3 = TKD[T] * 9 + TKH[T] * 3 + TKW[T];
        wB[idx] = f2bf(w[(ci * 64 + co) * 27 + k3]);
    }
}

#define MFMA(A, B, C) __builtin_amdgcn_mfma_f32_16x16x32_bf16((A), (B), (C), 0, 0, 0)

// grid = 16 b * 31 wd * 4 whg, 256 threads (R0 shell)
__global__ __launch_bounds__(256, 2) void main_kernel(const float* __restrict__ x,
                                                      const float* __restrict__ ws_ro,
                                                      float* __restrict__ accS) {
    __shared__ ushort_t xT[18432];  // [dd2][hh9][w32][ci32] bf16, s = kq ^ ((w>>1)&3)

    int bid = blockIdx.x;
    int b   = bid / 124;            // 31*4
    int r   = bid - b * 124;
    int wd  = r >> 2;               // [0,31)
    int whg = r & 3;                // wh group of 8
    int tid = threadIdx.x;
    int lane = tid & 63;
    int wave = tid >> 6;
    int uw   = __builtin_amdgcn_readfirstlane(wave);

    // ---- this wave's 27 weight B-frags (consumption order) -> regs (allocator-placed)
    const bf16x8* wBv = (const bf16x8*)((const char*)ws_ro + 4096);
    bf16x8 Bf[27];
#pragma unroll
    for (int t = 0; t < 27; ++t) Bf[t] = wBv[(uw * 27 + t) * 64 + lane];

    // ---- stage: wave uw stages ci planes [8uw,8uw+8); lane = (dd=lane>>5, w=lane&31)
    {
        int dd = lane >> 5;
        int wl = lane & 31;
        const float* xb = x + ((size_t)(b * 32 + uw * 8)) * 32768u
                            + ((size_t)(wd + 1) << 10) + ((size_t)(whg << 3) << 5);
        int voff = (dd - 1) * 1024 + wl;
        int ro8  = (whg == 3) ? 7 * 32 : 8 * 32;          // clamped last row (masked window only)
        int s    = uw ^ ((wl >> 1) & 3);
        ushort_t* dst = &xT[((dd * 9) << 10) + (wl << 5) + (s << 3)];
#pragma unroll
        for (int rr = 0; rr < 9; ++rr) {
            int ro = (rr < 8) ? rr * 32 : ro8;
            float v[8];
#pragma unroll
            for (int i = 0; i < 8; ++i) v[i] = xb[(size_t)i * 32768u + voff + ro];
            ushort8 pk;
#pragma unroll
            for (int i = 0; i < 4; ++i) {
                __hip_bfloat162 p2 = __float22bfloat162_rn(float2{v[2 * i], v[2 * i + 1]});
                pk[2 * i]     = __builtin_bit_cast(ushort_t, p2.x);
                pk[2 * i + 1] = __builtin_bit_cast(ushort_t, p2.y);
            }
            *(ushort8*)&dst[rr << 10] = pk;
        }
    }
    __syncthreads();

    // ---- phase stagger: co-resident pair (n, n+256) differ in bit 8 of bid.
    // Half a window-slot (~1150 cyc) shifts this block's burst/combine cadence by pi
    // relative to its CU partner; persists (identical cadence, no inter-block sync).
    if ((bid >> 8) & 1) __builtin_amdgcn_s_sleep(18);

    int m  = lane & 15;
    int kq = lane >> 4;
    const f32x4 Z = (f32x4){0.f, 0.f, 0.f, 0.f};

    f32x4 sumv0 = Z, sumv1 = Z;     // per-half window sums; ww-mask applied at end

#pragma unroll
    for (int half = 0; half < 2; ++half) {
        int wbase = half << 4;
        int w0 = wbase + m;                    // <= 31
        int w1 = w0 + 1; if (w1 > 31) w1 = 31; // garbage -> window 31, masked at end
        int col0 = (w0 << 5) + ((kq ^ ((w0 >> 1) & 3)) << 3);
        int col1 = (w1 << 5) + ((kq ^ ((w1 >> 1) & 3)) << 3);
        f32x4& sv = (half == 0) ? sumv0 : sumv1;   // static under unroll

#pragma unroll
        for (int win = 0; win < 8; ++win) {
            // F-reads for this window: rows win (FA), win+1 (FB); [dd][dw]
            bf16x8 FA[2][2], FB[2][2];
#pragma unroll
            for (int dd = 0; dd < 2; ++dd) {
                int rowA = (dd * 9 + win) << 10;
                int rowB = (dd * 9 + win + 1) << 10;
                FA[dd][0] = *(const bf16x8*)&xT[rowA + col0];
                FA[dd][1] = *(const bf16x8*)&xT[rowA + col1];
                FB[dd][0] = *(const bf16x8*)&xT[rowB + col0];
                FB[dd][1] = *(const bf16x8*)&xT[rowB + col1];
            }

            // 27 MFMAs, 9 independent chains, round-robin (mapping HW-verified R10/R12)
            __builtin_amdgcn_s_setprio(1);
            f32x4 C[9];
            C[0] = MFMA(FB[0][1], Bf[0],  Z);     // T0  (2,0,0)
            C[1] = MFMA(FB[1][1], Bf[1],  Z);     // T1  (0,0,0)
            C[2] = MFMA(FB[0][1], Bf[8],  Z);     // T8  (1,0,0)
            C[3] = MFMA(FA[1][1], Bf[9],  Z);     // T9  (0,1,0)
            C[4] = MFMA(FB[1][0], Bf[16], Z);     // T16 (0,0,1)
            C[5] = MFMA(FA[0][1], Bf[17], Z);     // T17 (1,1,0)
            C[6] = MFMA(FB[0][0], Bf[19], Z);     // T19 (1,0,1)
            C[7] = MFMA(FA[1][0], Bf[24], Z);     // T24 (0,1,1)
            C[8] = MFMA(FA[0][0], Bf[25], Z);     // T25 (1,1,1)
            C[0] = MFMA(FB[0][0], Bf[2],  C[0]);  // T2  (2,0,2)
            C[1] = MFMA(FB[1][0], Bf[3],  C[1]);  // T3  (0,0,2)
            C[2] = MFMA(FB[0][0], Bf[10], C[2]);  // T10 (1,0,2)
            C[3] = MFMA(FA[0][1], Bf[11], C[3]);  // T11 (2,1,0)
            C[4] = MFMA(FB[0][0], Bf[18], C[4]);  // T18 (2,0,1)
            C[5] = MFMA(FA[0][0], Bf[21], C[5]);  // T21 (1,1,2)
            C[6] = MFMA(FA[0][0], Bf[23], C[6]);  // T23 (1,2,1)
            C[7] = MFMA(FA[0][0], Bf[26], C[7]);  // T26 (2,1,1)
            C[0] = MFMA(FA[0][1], Bf[4],  C[0]);  // T4  (2,2,0)
            C[1] = MFMA(FA[1][1], Bf[5],  C[1]);  // T5  (0,2,0)
            C[2] = MFMA(FA[0][1], Bf[12], C[2]);  // T12 (1,2,0)
            C[3] = MFMA(FA[1][0], Bf[13], C[3]);  // T13 (0,1,2)
            C[4] = MFMA(FA[1][0], Bf[20], C[4]);  // T20 (0,2,1)
            C[0] = MFMA(FA[0][0], Bf[6],  C[0]);  // T6  (2,2,2)
            C[1] = MFMA(FA[1][0], Bf[7],  C[1]);  // T7  (0,2,2)
            C[2] = MFMA(FA[0][0], Bf[14], C[2]);  // T14 (1,2,2)
            C[3] = MFMA(FA[0][0], Bf[15], C[3]);  // T15 (2,1,2)
            C[4] = MFMA(FA[0][0], Bf[22], C[4]);  // T22 (2,2,1)
            __builtin_amdgcn_s_setprio(0);

            // immediate combine: max over 8 conv outputs, unconditional sumv add;
            // ww-mask applied once at end (R12-verified)
            int wh = (whg << 3) + win;
            if (wh < 31) {                        // uniform (false only whg=3,win=7)
#pragma unroll
                for (int i = 0; i < 4; ++i) {
                    float s0 = C[0][i] + C[1][i];                      // class (1,1,1) sum
                    float m1 = fmaxf(fmaxf(s0, C[2][i]), C[3][i]);     // v_max3
                    float m2 = fmaxf(fmaxf(C[4][i], C[5][i]), C[6][i]);// v_max3
                    float m3 = fmaxf(fmaxf(C[7][i], C[8][i]), m1);     // v_max3
                    sv[i] += fmaxf(m2, m3);
                }
            }
        }
    }

    // end-mask: half-0 rows ww=0..15 all valid; half-1 row rr=3 invalid iff kq==3 (ww=31)
    float runsum = sumv0[0] + sumv0[1] + sumv0[2] + sumv0[3]
                 + sumv1[0] + sumv1[1] + sumv1[2]
                 + ((kq == 3) ? 0.f : sumv1[3]);

    // lanes with same n=(lane&15) hold partials for the same co
    runsum += __shfl_xor(runsum, 16, 64);
    runsum += __shfl_xor(runsum, 32, 64);
    if (lane < 16) atomicAdd(&accS[(b << 6) + (wave << 4) + lane], runsum);
}

__global__ __launch_bounds__(256) void finalize_kernel(const float* __restrict__ accS,
                                                       const float* __restrict__ bias,
                                                       float* __restrict__ out) {
    int i = blockIdx.x * 256 + threadIdx.x;
    if (i < 1024) {
        int co = i & 63;
        float v = (accS[i] * (1.f / (float)NWIN) + bias[co]) * 0.5f;
        v = fminf(fmaxf(v, 0.f), 1.f);
        out[i] = v;
    }
}

extern "C" void kernel_launch(void* const* d_in, const int* in_sizes, int n_in,
                              void* d_out, int out_size, void* d_ws, size_t ws_size,
                              hipStream_t stream) {
    const float* x    = (const float*)d_in[0];
    const float* w    = (const float*)d_in[1];
    const float* bias = (const float*)d_in[2];
    float* out = (float*)d_out;
    float* ws  = (float*)d_ws;

    prep_kernel<<<216, 256, 0, stream>>>(w, ws);
    main_kernel<<<16 * 31 * 4, 256, 0, stream>>>(x, ws, ws);
    finalize_kernel<<<4, 256, 0, stream>>>(ws, bias, out);
}

// Round 9
// 327.285 us; speedup vs baseline: 1.5634x; 1.5634x over previous
//
#include <hip/hip_runtime.h>
#include <hip/hip_bf16.h>

// x[16,32,32,32,32] f32, w[32,64,3,3,3] f32, b[64] f32
// ConvTranspose3d(s=2,p=1,k=3) -> (+bias)*0.5 -> maxpool2 -> mean -> clamp[0,1] -> out[16,64]
//
// Window algebra (validated R0/R1, HW re-verified R10/R12): window w covers conv
// outputs {2w,2w+1}/dim, inputs {w,w+1}/dim. MFMA 16x16x32 bf16: M=16 ww-windows,
// N=16 co, K=32=Cin. Tap->frag rule: (kd,kh,kw) uses frag[dd=(kd==0)][dw=(kw==0)]
// of row wh+(kh==0).
//
// R15: clean phase-stagger probe (R14 minus setprio).
// SPILL LEDGER (hard-won): Bf[27] must be allocator-placed in AGPRs. Spill
// triggers so far: reg-staging across sched_barriers (R8/R9), 8-wave/512-thread
// launch bounds (R11), asm "+v" pin (R13), s_setprio pairs inside the unrolled
// loop (R14: VGPR 128 + 1.9GB scratch vs R12's clean 116 with identical data
// flow). NO side-effecting intrinsics inside the MFMA loop.
// Theory under test (T-A): co-resident block pairs (bid, bid+256) are wall-clock
// phase-locked; burst and combine phases coincide -> matrix pipe idles during
// the shared VALU phase. One-shot s_sleep(18) (~1150 cyc = half window slot) for
// odd (bid>>8)&1 blocks shifts the cadence by pi; persists (identical cadence).
// Alternative (T-B, if this is flat): AGPR-sourced B operand runs MFMA at ~half
// rate and 44% MfmaUtil is a saturated pipe mis-reported.
//
// ws: [0,4096)B accS[16][64] f32; [4096,...) wB bf16 [cotile4][T27][lane64][j8],
// T in exact consumption order (see TAP tables).

typedef __bf16 bf16x8 __attribute__((ext_vector_type(8)));
typedef float  f32x4  __attribute__((ext_vector_type(4)));
typedef unsigned short ushort_t;
typedef ushort_t ushort8 __attribute__((ext_vector_type(8)));

#define NWIN 29791  // 31^3

__device__ inline ushort_t f2bf(float f) {
    unsigned u = __builtin_bit_cast(unsigned, f);
    u += 0x7FFFu + ((u >> 16) & 1u);   // RNE
    return (ushort_t)(u >> 16);
}

// Consumption-order tap list (kd,kh,kw) for T=0..26
__device__ __constant__ const unsigned char TKD[27] = {2,0,2,0,2,0,2,0, 1,0,1,2,1,0,1,2, 0,1,2,1,0,1,2,1, 0,1,2};
__device__ __constant__ const unsigned char TKH[27] = {0,0,0,0,2,2,2,2, 0,1,0,1,2,1,2,1, 0,1,0,0,2,1,2,2, 1,1,1};
__device__ __constant__ const unsigned char TKW[27] = {0,0,2,2,0,0,2,2, 0,0,2,0,0,2,2,2, 1,0,1,1,1,2,1,1, 1,1,1};

__global__ __launch_bounds__(256) void prep_kernel(const float* __restrict__ w,
                                                   float* __restrict__ ws) {
    int idx = blockIdx.x * 256 + threadIdx.x;
    if (idx < 1024) ws[idx] = 0.f;
    if (idx < 55296) {
        ushort_t* wB = (ushort_t*)((char*)ws + 4096);
        int j = idx & 7;
        int l = (idx >> 3) & 63;
        int q = idx >> 9;           // [0,108) = c*27+T
        int T = q % 27;
        int c = q / 27;
        int ci = ((l >> 4) << 3) + j;
        int co = (c << 4) + (l & 15);
        int k3 = TKD[T] * 9 + TKH[T] * 3 + TKW[T];
        wB[idx] = f2bf(w[(ci * 64 + co) * 27 + k3]);
    }
}

#define MFMA(A, B, C) __builtin_amdgcn_mfma_f32_16x16x32_bf16((A), (B), (C), 0, 0, 0)

// grid = 16 b * 31 wd * 4 whg, 256 threads (R0 shell)
__global__ __launch_bounds__(256, 2) void main_kernel(const float* __restrict__ x,
                                                      const float* __restrict__ ws_ro,
                                                      float* __restrict__ accS) {
    __shared__ ushort_t xT[18432];  // [dd2][hh9][w32][ci32] bf16, s = kq ^ ((w>>1)&3)

    int bid = blockIdx.x;
    int b   = bid / 124;            // 31*4
    int r   = bid - b * 124;
    int wd  = r >> 2;               // [0,31)
    int whg = r & 3;                // wh group of 8
    int tid = threadIdx.x;
    int lane = tid & 63;
    int wave = tid >> 6;
    int uw   = __builtin_amdgcn_readfirstlane(wave);

    // ---- this wave's 27 weight B-frags (consumption order) -> regs (allocator-placed)
    const bf16x8* wBv = (const bf16x8*)((const char*)ws_ro + 4096);
    bf16x8 Bf[27];
#pragma unroll
    for (int t = 0; t < 27; ++t) Bf[t] = wBv[(uw * 27 + t) * 64 + lane];

    // ---- stage: wave uw stages ci planes [8uw,8uw+8); lane = (dd=lane>>5, w=lane&31)
    {
        int dd = lane >> 5;
        int wl = lane & 31;
        const float* xb = x + ((size_t)(b * 32 + uw * 8)) * 32768u
                            + ((size_t)(wd + 1) << 10) + ((size_t)(whg << 3) << 5);
        int voff = (dd - 1) * 1024 + wl;
        int ro8  = (whg == 3) ? 7 * 32 : 8 * 32;          // clamped last row (masked window only)
        int s    = uw ^ ((wl >> 1) & 3);
        ushort_t* dst = &xT[((dd * 9) << 10) + (wl << 5) + (s << 3)];
#pragma unroll
        for (int rr = 0; rr < 9; ++rr) {
            int ro = (rr < 8) ? rr * 32 : ro8;
            float v[8];
#pragma unroll
            for (int i = 0; i < 8; ++i) v[i] = xb[(size_t)i * 32768u + voff + ro];
            ushort8 pk;
#pragma unroll
            for (int i = 0; i < 4; ++i) {
                __hip_bfloat162 p2 = __float22bfloat162_rn(float2{v[2 * i], v[2 * i + 1]});
                pk[2 * i]     = __builtin_bit_cast(ushort_t, p2.x);
                pk[2 * i + 1] = __builtin_bit_cast(ushort_t, p2.y);
            }
            *(ushort8*)&dst[rr << 10] = pk;
        }
    }
    __syncthreads();

    // ---- phase stagger (one-shot, outside the unrolled loop): co-resident pair
    // (n, n+256) differ in bid bit 8. ~1150 cyc = half a window slot = pi shift.
    if ((bid >> 8) & 1) __builtin_amdgcn_s_sleep(18);

    int m  = lane & 15;
    int kq = lane >> 4;
    const f32x4 Z = (f32x4){0.f, 0.f, 0.f, 0.f};

    f32x4 sumv0 = Z, sumv1 = Z;     // per-half window sums; ww-mask applied at end

#pragma unroll
    for (int half = 0; half < 2; ++half) {
        int wbase = half << 4;
        int w0 = wbase + m;                    // <= 31
        int w1 = w0 + 1; if (w1 > 31) w1 = 31; // garbage -> window 31, masked at end
        int col0 = (w0 << 5) + ((kq ^ ((w0 >> 1) & 3)) << 3);
        int col1 = (w1 << 5) + ((kq ^ ((w1 >> 1) & 3)) << 3);
        f32x4& sv = (half == 0) ? sumv0 : sumv1;   // static under unroll

#pragma unroll
        for (int win = 0; win < 8; ++win) {
            // F-reads for this window: rows win (FA), win+1 (FB); [dd][dw]
            bf16x8 FA[2][2], FB[2][2];
#pragma unroll
            for (int dd = 0; dd < 2; ++dd) {
                int rowA = (dd * 9 + win) << 10;
                int rowB = (dd * 9 + win + 1) << 10;
                FA[dd][0] = *(const bf16x8*)&xT[rowA + col0];
                FA[dd][1] = *(const bf16x8*)&xT[rowA + col1];
                FB[dd][0] = *(const bf16x8*)&xT[rowB + col0];
                FB[dd][1] = *(const bf16x8*)&xT[rowB + col1];
            }

            // 27 MFMAs, 9 independent chains, round-robin (mapping HW-verified R10/R12)
            f32x4 C[9];
            C[0] = MFMA(FB[0][1], Bf[0],  Z);     // T0  (2,0,0)
            C[1] = MFMA(FB[1][1], Bf[1],  Z);     // T1  (0,0,0)
            C[2] = MFMA(FB[0][1], Bf[8],  Z);     // T8  (1,0,0)
            C[3] = MFMA(FA[1][1], Bf[9],  Z);     // T9  (0,1,0)
            C[4] = MFMA(FB[1][0], Bf[16], Z);     // T16 (0,0,1)
            C[5] = MFMA(FA[0][1], Bf[17], Z);     // T17 (1,1,0)
            C[6] = MFMA(FB[0][0], Bf[19], Z);     // T19 (1,0,1)
            C[7] = MFMA(FA[1][0], Bf[24], Z);     // T24 (0,1,1)
            C[8] = MFMA(FA[0][0], Bf[25], Z);     // T25 (1,1,1)
            C[0] = MFMA(FB[0][0], Bf[2],  C[0]);  // T2  (2,0,2)
            C[1] = MFMA(FB[1][0], Bf[3],  C[1]);  // T3  (0,0,2)
            C[2] = MFMA(FB[0][0], Bf[10], C[2]);  // T10 (1,0,2)
            C[3] = MFMA(FA[0][1], Bf[11], C[3]);  // T11 (2,1,0)
            C[4] = MFMA(FB[0][0], Bf[18], C[4]);  // T18 (2,0,1)
            C[5] = MFMA(FA[0][0], Bf[21], C[5]);  // T21 (1,1,2)
            C[6] = MFMA(FA[0][0], Bf[23], C[6]);  // T23 (1,2,1)
            C[7] = MFMA(FA[0][0], Bf[26], C[7]);  // T26 (2,1,1)
            C[0] = MFMA(FA[0][1], Bf[4],  C[0]);  // T4  (2,2,0)
            C[1] = MFMA(FA[1][1], Bf[5],  C[1]);  // T5  (0,2,0)
            C[2] = MFMA(FA[0][1], Bf[12], C[2]);  // T12 (1,2,0)
            C[3] = MFMA(FA[1][0], Bf[13], C[3]);  // T13 (0,1,2)
            C[4] = MFMA(FA[1][0], Bf[20], C[4]);  // T20 (0,2,1)
            C[0] = MFMA(FA[0][0], Bf[6],  C[0]);  // T6  (2,2,2)
            C[1] = MFMA(FA[1][0], Bf[7],  C[1]);  // T7  (0,2,2)
            C[2] = MFMA(FA[0][0], Bf[14], C[2]);  // T14 (1,2,2)
            C[3] = MFMA(FA[0][0], Bf[15], C[3]);  // T15 (2,1,2)
            C[4] = MFMA(FA[0][0], Bf[22], C[4]);  // T22 (2,2,1)

            // immediate combine: max over 8 conv outputs, unconditional sumv add;
            // ww-mask applied once at end (R12-verified)
            int wh = (whg << 3) + win;
            if (wh < 31) {                        // uniform (false only whg=3,win=7)
#pragma unroll
                for (int i = 0; i < 4; ++i) {
                    float s0 = C[0][i] + C[1][i];                      // class (1,1,1) sum
                    float m1 = fmaxf(fmaxf(s0, C[2][i]), C[3][i]);     // v_max3
                    float m2 = fmaxf(fmaxf(C[4][i], C[5][i]), C[6][i]);// v_max3
                    float m3 = fmaxf(fmaxf(C[7][i], C[8][i]), m1);     // v_max3
                    sv[i] += fmaxf(m2, m3);
                }
            }
        }
    }

    // end-mask: half-0 rows ww=0..15 all valid; half-1 row rr=3 invalid iff kq==3 (ww=31)
    float runsum = sumv0[0] + sumv0[1] + sumv0[2] + sumv0[3]
                 + sumv1[0] + sumv1[1] + sumv1[2]
                 + ((kq == 3) ? 0.f : sumv1[3]);

    // lanes with same n=(lane&15) hold partials for the same co
    runsum += __shfl_xor(runsum, 16, 64);
    runsum += __shfl_xor(runsum, 32, 64);
    if (lane < 16) atomicAdd(&accS[(b << 6) + (wave << 4) + lane], runsum);
}

__global__ __launch_bounds__(256) void finalize_kernel(const float* __restrict__ accS,
                                                       const float* __restrict__ bias,
                                                       float* __restrict__ out) {
    int i = blockIdx.x * 256 + threadIdx.x;
    if (i < 1024) {
        int co = i & 63;
        float v = (accS[i] * (1.f / (float)NWIN) + bias[co]) * 0.5f;
        v = fminf(fmaxf(v, 0.f), 1.f);
        out[i] = v;
    }
}

extern "C" void kernel_launch(void* const* d_in, const int* in_sizes, int n_in,
                              void* d_out, int out_size, void* d_ws, size_t ws_size,
                              hipStream_t stream) {
    const float* x    = (const float*)d_in[0];
    const float* w    = (const float*)d_in[1];
    const float* bias = (const float*)d_in[2];
    float* out = (float*)d_out;
    float* ws  = (float*)d_ws;

    prep_kernel<<<216, 256, 0, stream>>>(w, ws);
    main_kernel<<<16 * 31 * 4, 256, 0, stream>>>(x, ws, ws);
    finalize_kernel<<<4, 256, 0, stream>>>(ws, bias, out);
}

// Round 10
// 138.190 us; speedup vs baseline: 3.7027x; 2.3684x over previous
//
#include <hip/hip_runtime.h>
#include <hip/hip_bf16.h>

// x[16,32,32,32,32] f32, w[32,64,3,3,3] f32, b[64] f32
// ConvTranspose3d(s=2,p=1,k=3) -> (+bias)*0.5 -> maxpool2 -> mean -> clamp[0,1] -> out[16,64]
//
// Window algebra (validated R0/R1, HW re-verified R10/R12): window w covers conv
// outputs {2w,2w+1}/dim, inputs {w,w+1}/dim. MFMA 16x16x32 bf16: M=16 ww-windows,
// N=16 co, K=32=Cin. Tap->frag rule: (kd,kh,kw) -> F[dd=(kd==0)][dw=(kw==0)] of
// row win+(kh==0).
//
// R16: tap-split producer/consumer. REGISTER LAW (5 spills: R8,R9,R11,R13,R14/15):
// Bf[27]+C resident = ~208 unified regs/wave -> 2 waves/SIMD is structural and the
// allocation is knife-edge (any intrinsic/pin perturbation spills). MFMA floor is
// 26 us vs 52.3 measured -> need more waves/SIMD -> must SHRINK per-wave Bf.
// Split: wave pair per co-tile: th0 = 14 taps (classes eee/4 + oee + eeo + oeo),
// th1 = 13 taps (eee/4other + eoe + ooe + eoo + ooo). Class sums stay whole per
// wave except (e,e,e): its two 4-tap halves Ca,Cb exchange a SUM partial (safe).
// th0 publishes {CaP, max(oee,eeo,oeo)} per window via LDS (parity dbuf, 1
// barrier/window, count-matched across the role branches - HK producer/consumer
// pattern); th1 completes max{CaP+Cb, ...} and accumulates. Per-wave ~130 unified
// regs -> (256,3): 3 blocks/CU (LDS 44 KB), 3 waves/SIMD. Bf arrays loaded INSIDE
// each role branch so live ranges never overlap (the R8-R15 spill trigger).
// Grid x2 (co-half per block): FETCH ~140 MB, fine at 17% HBM.
//
// ws: [0,4096)B accS[16][64] f32; [4096,...) wB bf16 [coTile4][T27][lane64][j8]:
// T 0..13 = th0 taps, 14..26 = th1 taps, each in exact consumption order.

typedef __bf16 bf16x8 __attribute__((ext_vector_type(8)));
typedef float  f32x4  __attribute__((ext_vector_type(4)));
typedef unsigned short ushort_t;
typedef ushort_t ushort8 __attribute__((ext_vector_type(8)));

#define NWIN 29791  // 31^3

__device__ inline ushort_t f2bf(float f) {
    unsigned u = __builtin_bit_cast(unsigned, f);
    u += 0x7FFFu + ((u >> 16) & 1u);   // RNE
    return (ushort_t)(u >> 16);
}

// Tap tables, consumption order. T0..13 (th0): chains A=Ca(eee,kd=2-half),
// B=oee, C=eeo, D=oeo interleaved A0B0C0D0 A1B1C1D1 A2B2C2 A3B3C3.
// T14..26 (th1): A=Cb(eee,kd=0-half), B=eoe, C=ooe, D=eoo, E=ooo:
// A0B0C0D0E0 A1B1C1D1 A2B2 A3B3.
__device__ __constant__ const unsigned char TKD[27] =
    {2,1,0,1, 2,1,2,1, 2,1,0, 2,1,2,   0,0,1,0,1, 0,0,1,2, 0,2, 0,2};
__device__ __constant__ const unsigned char TKH[27] =
    {0,0,0,0, 0,0,0,2, 2,2,2, 2,2,2,   0,1,1,1,1, 0,1,1,1, 2,1, 2,1};
__device__ __constant__ const unsigned char TKW[27] =
    {0,0,1,1, 2,2,1,1, 0,0,1, 2,2,1,   0,0,0,1,1, 2,2,2,1, 0,0, 2,2};

__global__ __launch_bounds__(256) void prep_kernel(const float* __restrict__ w,
                                                   float* __restrict__ ws) {
    int idx = blockIdx.x * 256 + threadIdx.x;
    if (idx < 1024) ws[idx] = 0.f;
    if (idx < 55296) {
        ushort_t* wB = (ushort_t*)((char*)ws + 4096);
        int j = idx & 7;
        int l = (idx >> 3) & 63;
        int q = idx >> 9;           // [0,108) = c*27+T
        int T = q % 27;
        int c = q / 27;
        int ci = ((l >> 4) << 3) + j;
        int co = (c << 4) + (l & 15);
        int k3 = TKD[T] * 9 + TKH[T] * 3 + TKW[T];
        wB[idx] = f2bf(w[(ci * 64 + co) * 27 + k3]);
    }
}

#define MFMA(A, B, C) __builtin_amdgcn_mfma_f32_16x16x32_bf16((A), (B), (C), 0, 0, 0)

// grid = 16 b * 31 wd * 4 whg * 2 ch, 256 threads.
// wave uw: ct = uw&1 (co-tile within half), th = uw>>1 (tap-half role).
__global__ __launch_bounds__(256, 3) void main_kernel(const float* __restrict__ x,
                                                      const float* __restrict__ ws_ro,
                                                      float* __restrict__ accS) {
    __shared__ ushort_t xT[18432];  // [dd2][hh9][w32][ci32] bf16, s = kq ^ ((w>>1)&3)
    __shared__ f32x4 xch[512];      // exchange: [(par*2+ct)*2+item][lane]; 8 KB

    int bid = blockIdx.x;
    int b   = bid / 248;            // 31*4*2
    int r   = bid - b * 248;
    int wd  = r >> 3;               // [0,31)
    int r2  = r & 7;
    int whg = r2 >> 1;              // wh group of 8
    int ch  = r2 & 1;               // co half (co base 32*ch)
    int tid = threadIdx.x;
    int lane = tid & 63;
    int wave = tid >> 6;
    int uw   = __builtin_amdgcn_readfirstlane(wave);
    int ct   = uw & 1;              // co-tile within half
    int th   = uw >> 1;             // role: 0 producer-half taps, 1 consumer-half
    int cg   = (ch << 1) + ct;      // global co-tile 0..3

    int m  = lane & 15;
    int kq = lane >> 4;
    const f32x4 Z = (f32x4){0.f, 0.f, 0.f, 0.f};
    const bf16x8* wBv = (const bf16x8*)((const char*)ws_ro + 4096);

    // ---- staging lambda (identical to R0's proven code); wave uw stages ci
    // planes [8uw, 8uw+8)
    auto stage = [&]() {
        int dd = lane >> 5;
        int wl = lane & 31;
        const float* xb = x + ((size_t)(b * 32 + uw * 8)) * 32768u
                            + ((size_t)(wd + 1) << 10) + ((size_t)(whg << 3) << 5);
        int voff = (dd - 1) * 1024 + wl;
        int ro8  = (whg == 3) ? 7 * 32 : 8 * 32;      // clamped last row (masked window)
        int s    = uw ^ ((wl >> 1) & 3);
        ushort_t* dst = &xT[((dd * 9) << 10) + (wl << 5) + (s << 3)];
#pragma unroll
        for (int rr = 0; rr < 9; ++rr) {
            int ro = (rr < 8) ? rr * 32 : ro8;
            float v[8];
#pragma unroll
            for (int i = 0; i < 8; ++i) v[i] = xb[(size_t)i * 32768u + voff + ro];
            ushort8 pk;
#pragma unroll
            for (int i = 0; i < 4; ++i) {
                __hip_bfloat162 p2 = __float22bfloat162_rn(float2{v[2 * i], v[2 * i + 1]});
                pk[2 * i]     = __builtin_bit_cast(ushort_t, p2.x);
                pk[2 * i + 1] = __builtin_bit_cast(ushort_t, p2.y);
            }
            *(ushort8*)&dst[rr << 10] = pk;
        }
    };

    if (th == 0) {
        // ================= producer-half role: 14 taps =================
        bf16x8 Bf[14];
#pragma unroll
        for (int t = 0; t < 14; ++t) Bf[t] = wBv[(cg * 27 + t) * 64 + lane];
        stage();
        __syncthreads();

#pragma unroll
        for (int half = 0; half < 2; ++half) {
            int wbase = half << 4;
            int w0 = wbase + m;
            int w1 = w0 + 1; if (w1 > 31) w1 = 31;   // garbage -> masked in th1
            int col0 = (w0 << 5) + ((kq ^ ((w0 >> 1) & 3)) << 3);
            int col1 = (w1 << 5) + ((kq ^ ((w1 >> 1) & 3)) << 3);

#pragma unroll
            for (int win = 0; win < 8; ++win) {
                int par = ((half << 3) + win) & 1;
                int rA0 = (win) << 10, rB0 = (win + 1) << 10;
                int rA1 = (9 + win) << 10, rB1 = (9 + win + 1) << 10;
                // needed frags: FA00 FA01 FA10 FB00 FB01 FB10
                bf16x8 FA00 = *(const bf16x8*)&xT[rA0 + col0];
                bf16x8 FA01 = *(const bf16x8*)&xT[rA0 + col1];
                bf16x8 FA10 = *(const bf16x8*)&xT[rA1 + col0];
                bf16x8 FB00 = *(const bf16x8*)&xT[rB0 + col0];
                bf16x8 FB01 = *(const bf16x8*)&xT[rB0 + col1];
                bf16x8 FB10 = *(const bf16x8*)&xT[rB1 + col0];

                f32x4 CA, CB, CC, CD;
                CA = MFMA(FB01, Bf[0],  Z);   // (2,0,0)
                CB = MFMA(FB01, Bf[1],  Z);   // (1,0,0)
                CC = MFMA(FB10, Bf[2],  Z);   // (0,0,1)
                CD = MFMA(FB00, Bf[3],  Z);   // (1,0,1)
                CA = MFMA(FB00, Bf[4],  CA);  // (2,0,2)
                CB = MFMA(FB00, Bf[5],  CB);  // (1,0,2)
                CC = MFMA(FB00, Bf[6],  CC);  // (2,0,1)
                CD = MFMA(FA00, Bf[7],  CD);  // (1,2,1)
                CA = MFMA(FA01, Bf[8],  CA);  // (2,2,0)
                CB = MFMA(FA01, Bf[9],  CB);  // (1,2,0)
                CC = MFMA(FA10, Bf[10], CC);  // (0,2,1)
                CA = MFMA(FA00, Bf[11], CA);  // (2,2,2)
                CB = MFMA(FA00, Bf[12], CB);  // (1,2,2)
                CC = MFMA(FA00, Bf[13], CC);  // (2,2,1)

                f32x4 M0;
#pragma unroll
                for (int i = 0; i < 4; ++i)
                    M0[i] = fmaxf(fmaxf(CB[i], CC[i]), CD[i]);  // max(oee,eeo,oeo)
                xch[((par * 2 + ct) * 2 + 0) * 64 + lane] = CA; // CaP (sum partial)
                xch[((par * 2 + ct) * 2 + 1) * 64 + lane] = M0;
                __syncthreads();
            }
        }
    } else {
        // ================= consumer-half role: 13 taps =================
        bf16x8 Bf[13];
#pragma unroll
        for (int t = 0; t < 13; ++t) Bf[t] = wBv[(cg * 27 + 14 + t) * 64 + lane];
        stage();
        __syncthreads();

        float runsum = 0.f;
#pragma unroll
        for (int half = 0; half < 2; ++half) {
            int wbase = half << 4;
            int w0 = wbase + m;
            int w1 = w0 + 1; if (w1 > 31) w1 = 31;
            int col0 = (w0 << 5) + ((kq ^ ((w0 >> 1) & 3)) << 3);
            int col1 = (w1 << 5) + ((kq ^ ((w1 >> 1) & 3)) << 3);

#pragma unroll
            for (int win = 0; win < 8; ++win) {
                int par = ((half << 3) + win) & 1;
                int rA0 = (win) << 10, rB1 = (9 + win + 1) << 10;
                int rA1 = (9 + win) << 10;
                // needed frags: FA00 FA01 FA10 FA11 FB10 FB11
                bf16x8 FA00 = *(const bf16x8*)&xT[rA0 + col0];
                bf16x8 FA01 = *(const bf16x8*)&xT[rA0 + col1];
                bf16x8 FA10 = *(const bf16x8*)&xT[rA1 + col0];
                bf16x8 FA11 = *(const bf16x8*)&xT[rA1 + col1];
                bf16x8 FB10 = *(const bf16x8*)&xT[rB1 + col0];
                bf16x8 FB11 = *(const bf16x8*)&xT[rB1 + col1];

                f32x4 CA, CB, CC, CD, CE;
                CA = MFMA(FB11, Bf[0],  Z);   // (0,0,0)
                CB = MFMA(FA11, Bf[1],  Z);   // (0,1,0)
                CC = MFMA(FA01, Bf[2],  Z);   // (1,1,0)
                CD = MFMA(FA10, Bf[3],  Z);   // (0,1,1)
                CE = MFMA(FA00, Bf[4],  Z);   // (1,1,1)
                CA = MFMA(FB10, Bf[5],  CA);  // (0,0,2)
                CB = MFMA(FA10, Bf[6],  CB);  // (0,1,2)
                CC = MFMA(FA00, Bf[7],  CC);  // (1,1,2)
                CD = MFMA(FA00, Bf[8],  CD);  // (2,1,1)
                CA = MFMA(FA11, Bf[9],  CA);  // (0,2,0)
                CB = MFMA(FA01, Bf[10], CB);  // (2,1,0)
                CA = MFMA(FA10, Bf[11], CA);  // (0,2,2)
                CB = MFMA(FA00, Bf[12], CB);  // (2,1,2)

                __syncthreads();
                int wh = (whg << 3) + win;
                if (wh < 31) {                 // uniform (false only whg=3,win=7)
                    f32x4 P0 = xch[((par * 2 + ct) * 2 + 0) * 64 + lane];  // CaP
                    f32x4 P1 = xch[((par * 2 + ct) * 2 + 1) * 64 + lane];  // M0
#pragma unroll
                    for (int i = 0; i < 4; ++i) {
                        float s0 = P0[i] + CA[i];                        // full eee sum
                        float m1 = fmaxf(fmaxf(s0, P1[i]), CB[i]);       // v_max3
                        float m2 = fmaxf(fmaxf(CC[i], CD[i]), CE[i]);    // v_max3
                        float mx = fmaxf(m1, m2);
                        int ww = wbase + (kq << 2) + i;
                        if (ww < 31) runsum += mx;
                    }
                }
            }
        }

        // lanes with same n=(lane&15) hold partials for the same co
        runsum += __shfl_xor(runsum, 16, 64);
        runsum += __shfl_xor(runsum, 32, 64);
        if (lane < 16) atomicAdd(&accS[(b << 6) + (cg << 4) + lane], runsum);
    }
}

__global__ __launch_bounds__(256) void finalize_kernel(const float* __restrict__ accS,
                                                       const float* __restrict__ bias,
                                                       float* __restrict__ out) {
    int i = blockIdx.x * 256 + threadIdx.x;
    if (i < 1024) {
        int co = i & 63;
        float v = (accS[i] * (1.f / (float)NWIN) + bias[co]) * 0.5f;
        v = fminf(fmaxf(v, 0.f), 1.f);
        out[i] = v;
    }
}

extern "C" void kernel_launch(void* const* d_in, const int* in_sizes, int n_in,
                              void* d_out, int out_size, void* d_ws, size_t ws_size,
                              hipStream_t stream) {
    const float* x    = (const float*)d_in[0];
    const float* w    = (const float*)d_in[1];
    const float* bias = (const float*)d_in[2];
    float* out = (float*)d_out;
    float* ws  = (float*)d_ws;

    prep_kernel<<<216, 256, 0, stream>>>(w, ws);
    main_kernel<<<16 * 31 * 4 * 2, 256, 0, stream>>>(x, ws, ws);
    finalize_kernel<<<4, 256, 0, stream>>>(ws, bias, out);
}